// Round 1
// baseline (827.718 us; speedup 1.0000x reference)
//
#include <hip/hip_runtime.h>
#include <math.h>

#define Bdim 32
#define Adim 256
#define Ndim 64
#define Gdim 50
#define Fdim 128

// ---------------------------------------------------------------------------
// Kernel 1: y[r,f] = sum_i x[r,i] * w[i,f]    (rows = B*A = 8192)
// 512 blocks x 16 rows. w (64KB) + x-tile (8KB) staged in LDS -> 2 blocks/CU.
// Each thread owns 4 rows x 2 cols; i-unrolled by 2 with float2 x reads.
// ---------------------------------------------------------------------------
__global__ __launch_bounds__(256) void in2f_kernel(const float* __restrict__ x,
                                                   const float* __restrict__ w,
                                                   float* __restrict__ y) {
    __shared__ float sW[Fdim * Fdim];   // 64 KB
    __shared__ float sX[16 * Fdim];     // 8 KB
    const int tid = threadIdx.x;
    const int row0 = blockIdx.x * 16;

    for (int idx = tid; idx < Fdim * Fdim; idx += 256) sW[idx] = w[idx];
    for (int idx = tid; idx < 16 * Fdim; idx += 256)
        sX[idx] = x[(size_t)row0 * Fdim + idx];
    __syncthreads();

    const int fg = tid & 63;   // f in {fg, fg+64}
    const int rg = tid >> 6;   // rows rg*4 .. rg*4+3
    float acc[4][2] = {};
    for (int i = 0; i < Fdim; i += 2) {
        float w00 = sW[i * Fdim + fg];
        float w01 = sW[i * Fdim + fg + 64];
        float w10 = sW[(i + 1) * Fdim + fg];
        float w11 = sW[(i + 1) * Fdim + fg + 64];
#pragma unroll
        for (int k = 0; k < 4; ++k) {
            float2 xv = *(const float2*)&sX[(rg * 4 + k) * Fdim + i];
            acc[k][0] += xv.x * w00 + xv.y * w10;
            acc[k][1] += xv.x * w01 + xv.y * w11;
        }
    }
#pragma unroll
    for (int k = 0; k < 4; ++k) {
        int r = row0 + rg * 4 + k;
        y[(size_t)r * Fdim + fg]      = acc[k][0];
        y[(size_t)r * Fdim + fg + 64] = acc[k][1];
    }
}

// ---------------------------------------------------------------------------
// Kernel 2: fused filter-net + cutoff + gather + neighbor reduction.
// One block per (b,a). LDS: f_ij tile (13KB, padded 50->52), fw1/fw2-chunk
// buffer (25.6KB, aliased), W1 (32KB), Cm + nbr (small). Total ~72KB.
// Thread tile: 8 n-rows x 4 f-cols (fg = tid&31 -> f = fg+32j; ng = tid>>5).
// ---------------------------------------------------------------------------
__global__ __launch_bounds__(256) void cfconv_kernel(
    const float* __restrict__ r_ij, const float* __restrict__ f_ij,
    const float* __restrict__ mask, const int* __restrict__ nbr,
    const float* __restrict__ fw1, const float* __restrict__ fb1,
    const float* __restrict__ fw2, const float* __restrict__ fb2,
    const float* __restrict__ y, float* __restrict__ out)
{
    __shared__ float sF[Ndim * 52];       // 13312 B; reused as sRed (1024 fl)
    __shared__ float sBuf[Gdim * Fdim];   // 25600 B; fw1, then fw2 chunks
    __shared__ float sW1[Ndim * Fdim];    // 32768 B
    __shared__ float sCm[Ndim];
    __shared__ int   sNbr[Ndim];

    const int tid = threadIdx.x;
    const int p = blockIdx.x;       // b*A + a
    const int b = p >> 8;           // A = 256

    // ---- phase A: stage f_ij tile, fw1, cutoff*mask, neighbor indices ----
    for (int idx = tid; idx < Ndim * Gdim; idx += 256) {
        int n = idx / Gdim, g = idx - n * Gdim;
        sF[n * 52 + g] = f_ij[(size_t)p * (Ndim * Gdim) + idx];
    }
    for (int idx = tid; idx < Gdim * Fdim; idx += 256) sBuf[idx] = fw1[idx];
    if (tid < Ndim) {
        float r = r_ij[(size_t)p * Ndim + tid];
        float c = 0.5f * (__cosf(r * 0.62831853071f) + 1.0f);  // pi/5
        c = (r < 5.0f) ? c : 0.0f;
        sCm[tid]  = c * mask[(size_t)p * Ndim + tid];
        sNbr[tid] = nbr[(size_t)p * Ndim + tid];
    }
    __syncthreads();

    const int fg = tid & 31;   // f = fg + 32*j, j = 0..3
    const int ng = tid >> 5;   // n = ng*8 + k, k = 0..7

    // ---- phase B: W1 = ssp(f_ij @ fw1 + fb1)   (64x50)@(50x128) ----
    {
        float acc[8][4] = {};
        for (int g = 0; g < Gdim; g += 2) {
            float w0[4], w1[4];
#pragma unroll
            for (int j = 0; j < 4; ++j) {
                w0[j] = sBuf[g * Fdim + fg + 32 * j];
                w1[j] = sBuf[(g + 1) * Fdim + fg + 32 * j];
            }
#pragma unroll
            for (int k = 0; k < 8; ++k) {
                float2 fv = *(const float2*)&sF[(ng * 8 + k) * 52 + g];
#pragma unroll
                for (int j = 0; j < 4; ++j)
                    acc[k][j] += fv.x * w0[j] + fv.y * w1[j];
            }
        }
#pragma unroll
        for (int j = 0; j < 4; ++j) {
            float bias = fb1[fg + 32 * j];
#pragma unroll
            for (int k = 0; k < 8; ++k) {
                float v = acc[k][j] + bias;
                float sp = (v > 20.0f) ? v : log1pf(__expf(v));  // softplus
                sW1[(ng * 8 + k) * Fdim + fg + 32 * j] = sp - 0.69314718056f;
            }
        }
    }
    __syncthreads();

    // ---- phase C: W2 = W1 @ fw2 (64x128)@(128x128), h chunked by 32 ----
    float acc[8][4] = {};
    for (int hc = 0; hc < Fdim; hc += 32) {
        for (int idx = tid; idx < 32 * Fdim; idx += 256)
            sBuf[idx] = fw2[(size_t)hc * Fdim + idx];
        __syncthreads();
        for (int h = 0; h < 32; h += 4) {
            float rw[4][4];
#pragma unroll
            for (int hh = 0; hh < 4; ++hh)
#pragma unroll
                for (int j = 0; j < 4; ++j)
                    rw[hh][j] = sBuf[(h + hh) * Fdim + fg + 32 * j];
#pragma unroll
            for (int k = 0; k < 8; ++k) {
                float4 wv = *(const float4*)&sW1[(ng * 8 + k) * Fdim + hc + h];
#pragma unroll
                for (int j = 0; j < 4; ++j)
                    acc[k][j] += wv.x * rw[0][j] + wv.y * rw[1][j]
                               + wv.z * rw[2][j] + wv.w * rw[3][j];
            }
        }
        __syncthreads();
    }

    // ---- epilogue: out[f] = sum_n Cm[n]*(W2[n,f]+fb2[f]) * y[nbr[n],f] ----
    float part[4] = {0.f, 0.f, 0.f, 0.f};
    float bias2[4];
#pragma unroll
    for (int j = 0; j < 4; ++j) bias2[j] = fb2[fg + 32 * j];
#pragma unroll
    for (int k = 0; k < 8; ++k) {
        int n = ng * 8 + k;
        float cm = sCm[n];
        const float* yrow = y + (size_t)(b * Adim + sNbr[n]) * Fdim;
#pragma unroll
        for (int j = 0; j < 4; ++j)
            part[j] += (acc[k][j] + bias2[j]) * cm * yrow[fg + 32 * j];
    }
    // reduce the 8 n-groups (sF region is free now)
    float* sRed = sF;
#pragma unroll
    for (int j = 0; j < 4; ++j) sRed[ng * Fdim + fg + 32 * j] = part[j];
    __syncthreads();
    if (tid < Fdim) {
        float s = 0.f;
#pragma unroll
        for (int g2 = 0; g2 < 8; ++g2) s += sRed[g2 * Fdim + tid];
        out[(size_t)p * Fdim + tid] = s;
    }
}

// ---------------------------------------------------------------------------
extern "C" void kernel_launch(void* const* d_in, const int* in_sizes, int n_in,
                              void* d_out, int out_size, void* d_ws, size_t ws_size,
                              hipStream_t stream) {
    const float* x      = (const float*)d_in[0];
    const float* r_ij   = (const float*)d_in[1];
    const float* f_ij   = (const float*)d_in[2];
    const float* mask   = (const float*)d_in[3];
    const int*   nbr    = (const int*)d_in[4];
    const float* in2f_w = (const float*)d_in[5];
    const float* fw1    = (const float*)d_in[6];
    const float* fb1    = (const float*)d_in[7];
    const float* fw2    = (const float*)d_in[8];
    const float* fb2    = (const float*)d_in[9];
    float* out = (float*)d_out;
    float* y   = (float*)d_ws;   // (B*A, F) fp32 = 4 MB scratch

    in2f_kernel<<<(Bdim * Adim) / 16, 256, 0, stream>>>(x, in2f_w, y);
    cfconv_kernel<<<Bdim * Adim, 256, 0, stream>>>(r_ij, f_ij, mask, nbr,
                                                   fw1, fb1, fw2, fb2, y, out);
}

// Round 2
// 336.706 us; speedup vs baseline: 2.4583x; 2.4583x over previous
//
#include <hip/hip_runtime.h>
#include <math.h>

#define Bdim 32
#define Adim 256
#define Ndim 64
#define Gdim 50
#define Fdim 128

typedef __attribute__((ext_vector_type(8)))  short short8;
typedef __attribute__((ext_vector_type(4)))  short short4v;
typedef __attribute__((ext_vector_type(16))) float floatx16;

__device__ __forceinline__ short f2bf(float x) {
    unsigned u = __builtin_bit_cast(unsigned, x);
    u = (u + 0x7FFFu + ((u >> 16) & 1u)) >> 16;   // RNE
    return (short)u;
}

// shifted softplus, numerically stable
__device__ __forceinline__ float ssp(float v) {
    return fmaxf(v, 0.0f) + __logf(1.0f + __expf(-fabsf(v))) - 0.69314718056f;
}

// ---------------------------------------------------------------------------
// Kernel 1 (unchanged from round 1): y[r,f] = sum_i x[r,i] * in2f_w[i,f]
// ---------------------------------------------------------------------------
__global__ __launch_bounds__(256) void in2f_kernel(const float* __restrict__ x,
                                                   const float* __restrict__ w,
                                                   float* __restrict__ y) {
    __shared__ float sW[Fdim * Fdim];
    __shared__ float sX[16 * Fdim];
    const int tid = threadIdx.x;
    const int row0 = blockIdx.x * 16;

    for (int idx = tid; idx < Fdim * Fdim; idx += 256) sW[idx] = w[idx];
    for (int idx = tid; idx < 16 * Fdim; idx += 256)
        sX[idx] = x[(size_t)row0 * Fdim + idx];
    __syncthreads();

    const int fg = tid & 63;
    const int rg = tid >> 6;
    float acc[4][2] = {};
    for (int i = 0; i < Fdim; i += 2) {
        float w00 = sW[i * Fdim + fg];
        float w01 = sW[i * Fdim + fg + 64];
        float w10 = sW[(i + 1) * Fdim + fg];
        float w11 = sW[(i + 1) * Fdim + fg + 64];
#pragma unroll
        for (int k = 0; k < 4; ++k) {
            float2 xv = *(const float2*)&sX[(rg * 4 + k) * Fdim + i];
            acc[k][0] += xv.x * w00 + xv.y * w10;
            acc[k][1] += xv.x * w01 + xv.y * w11;
        }
    }
#pragma unroll
    for (int k = 0; k < 4; ++k) {
        int r = row0 + rg * 4 + k;
        y[(size_t)r * Fdim + fg]      = acc[k][0];
        y[(size_t)r * Fdim + fg + 64] = acc[k][1];
    }
}

// ---------------------------------------------------------------------------
// Kernel 2: MFMA filter-net + cutoff + gather + neighbor reduction.
// One block = one "super-pair" (2 (b,a) pairs stacked -> M=128) per iteration,
// 4 iterations. Weights staged once per block in transposed bf16 LDS layouts.
//
// dense1: W1T[f][row] = ssp( fw1T[f][g] @ f_ijT[g][row] + fb1 )  via MFMA
//         (A = fw1T so D-regs are 4 consecutive f -> b64 writes of W1[row][f])
// dense2: W2[row][f] = W1[row][h] @ fw2T[f][h]^T
// epilogue: out[p][f] = sum_n Cm[n]*(W2[n][f]+fb2[f])*y[nbr[n]][f]
//
// LDS strides padded to (4 mod 32) dwords -> conflict-free ds_read_b128.
// ---------------------------------------------------------------------------
#define S1 72    // g-dim: 50 -> pad K to 64, stride 72 shorts (36 dw)
#define S2 136   // h/f-dim: 128, stride 136 shorts (68 dw)

__global__ __launch_bounds__(256) void cfconv_mfma(
    const float* __restrict__ r_ij, const float* __restrict__ f_ij,
    const float* __restrict__ mask, const int* __restrict__ nbr,
    const float* __restrict__ fw1, const float* __restrict__ fb1,
    const float* __restrict__ fw2, const float* __restrict__ fb2,
    const float* __restrict__ y, float* __restrict__ out)
{
    __shared__ __align__(16) short sFw1[128 * S1];  // fw1T[f][g]      18.4 KB
    __shared__ __align__(16) short sFw2[128 * S2];  // fw2T[f][h]      34.8 KB
    __shared__ __align__(16) short sFij[128 * S1];  // [(pair,n)][g]   18.4 KB
    __shared__ __align__(16) short sW1 [128 * S2];  // [(pair,n)][h]   34.8 KB
    __shared__ float sCm[128];
    __shared__ int   sNbr[128];
    __shared__ float sFb1[128];
    __shared__ float sFb2[128];

    const int tid  = threadIdx.x;
    const int w    = tid >> 6;
    const int lane = tid & 63;
    const int lm   = lane & 31;
    const int lh   = lane >> 5;

    // ---- stage weights once per block ----
    for (int idx = tid; idx < Gdim * Fdim; idx += 256) {
        int g = idx >> 7, f = idx & 127;
        sFw1[f * S1 + g] = f2bf(fw1[idx]);
    }
    for (int idx = tid; idx < 128 * 14; idx += 256) {   // zero-pad g = 50..63
        int f = idx / 14, g = Gdim + idx % 14;
        sFw1[f * S1 + g] = 0;
    }
    for (int idx = tid; idx < Fdim * Fdim; idx += 256) {
        int h = idx >> 7, f = idx & 127;
        sFw2[f * S2 + h] = f2bf(fw2[idx]);
    }
    if (tid < 128) { sFb1[tid] = fb1[tid]; sFb2[tid] = fb2[tid]; }

    for (int it = 0; it < 4; ++it) {
        const int sp = blockIdx.x + 1024 * it;
        const int p0 = sp * 2;

        __syncthreads();   // B0: previous iteration fully done before restage

        // ---- stage f_ij tile (bf16) + cutoff/mask + neighbor indices ----
        const float* fp = f_ij + (size_t)p0 * (Ndim * Gdim);
        for (int idx = tid; idx < 2 * Ndim * Gdim; idx += 256) {
            int row = idx / Gdim, g = idx - row * Gdim;
            sFij[row * S1 + g] = f2bf(fp[idx]);
        }
        for (int idx = tid; idx < 128 * 14; idx += 256) {
            int r = idx / 14, g = Gdim + idx % 14;
            sFij[r * S1 + g] = 0;
        }
        if (tid < 128) {
            int pp = p0 + (tid >> 6), n = tid & 63;
            float r = r_ij[pp * Ndim + n];
            float c = 0.5f * (__cosf(r * 0.62831853071796f) + 1.0f);
            c = (r < 5.0f) ? c : 0.0f;
            sCm[tid]  = c * mask[pp * Ndim + n];
            sNbr[tid] = nbr[pp * Ndim + n];
        }
        __syncthreads();   // B1

        // ---- dense1: A = fw1T (M=f), B = f_ijT (N=row), K = 64 ----
        {
            const int fbase = (w >> 1) * 64;
            const int nbase = (w & 1) * 64;
            floatx16 acc1[2][2];
#pragma unroll
            for (int i = 0; i < 2; ++i)
#pragma unroll
                for (int j = 0; j < 2; ++j)
#pragma unroll
                    for (int e = 0; e < 16; ++e) acc1[i][j][e] = 0.0f;
#pragma unroll
            for (int ks = 0; ks < 4; ++ks) {
                int k0 = ks * 16 + 8 * lh;
                short8 a0 = *(const short8*)&sFw1[(fbase + lm) * S1 + k0];
                short8 a1 = *(const short8*)&sFw1[(fbase + 32 + lm) * S1 + k0];
                short8 b0 = *(const short8*)&sFij[(nbase + lm) * S1 + k0];
                short8 b1 = *(const short8*)&sFij[(nbase + 32 + lm) * S1 + k0];
                acc1[0][0] = __builtin_amdgcn_mfma_f32_32x32x16_bf16(a0, b0, acc1[0][0], 0, 0, 0);
                acc1[0][1] = __builtin_amdgcn_mfma_f32_32x32x16_bf16(a0, b1, acc1[0][1], 0, 0, 0);
                acc1[1][0] = __builtin_amdgcn_mfma_f32_32x32x16_bf16(a1, b0, acc1[1][0], 0, 0, 0);
                acc1[1][1] = __builtin_amdgcn_mfma_f32_32x32x16_bf16(a1, b1, acc1[1][1], 0, 0, 0);
            }
            // ssp + pack 4 consecutive f (D rows) -> b64 write of W1[row][f]
#pragma unroll
            for (int i = 0; i < 2; ++i) {
#pragma unroll
                for (int rg = 0; rg < 4; ++rg) {
                    int f0 = fbase + i * 32 + 8 * rg + 4 * lh;
                    float b4[4] = { sFb1[f0], sFb1[f0 + 1], sFb1[f0 + 2], sFb1[f0 + 3] };
#pragma unroll
                    for (int j = 0; j < 2; ++j) {
                        int n = nbase + j * 32 + lm;
                        short4v pk;
#pragma unroll
                        for (int q = 0; q < 4; ++q)
                            pk[q] = f2bf(ssp(acc1[i][j][rg * 4 + q] + b4[q]));
                        *(short4v*)&sW1[n * S2 + f0] = pk;
                    }
                }
            }
        }
        __syncthreads();   // B2

        // ---- dense2: A = W1 (M=row), B = fw2T (N=f), K = 128 ----
        const int wm = w >> 1;          // pair within super-pair
        const int wn = w & 1;           // f half
        const int rbase = wm * 64;
        const int fbase2 = wn * 64;
        floatx16 acc2[2][2];
#pragma unroll
        for (int i = 0; i < 2; ++i)
#pragma unroll
            for (int j = 0; j < 2; ++j)
#pragma unroll
                for (int e = 0; e < 16; ++e) acc2[i][j][e] = 0.0f;
#pragma unroll
        for (int ks = 0; ks < 8; ++ks) {
            int k0 = ks * 16 + 8 * lh;
            short8 a0 = *(const short8*)&sW1[(rbase + lm) * S2 + k0];
            short8 a1 = *(const short8*)&sW1[(rbase + 32 + lm) * S2 + k0];
            short8 b0 = *(const short8*)&sFw2[(fbase2 + lm) * S2 + k0];
            short8 b1 = *(const short8*)&sFw2[(fbase2 + 32 + lm) * S2 + k0];
            acc2[0][0] = __builtin_amdgcn_mfma_f32_32x32x16_bf16(a0, b0, acc2[0][0], 0, 0, 0);
            acc2[0][1] = __builtin_amdgcn_mfma_f32_32x32x16_bf16(a0, b1, acc2[0][1], 0, 0, 0);
            acc2[1][0] = __builtin_amdgcn_mfma_f32_32x32x16_bf16(a1, b0, acc2[1][0], 0, 0, 0);
            acc2[1][1] = __builtin_amdgcn_mfma_f32_32x32x16_bf16(a1, b1, acc2[1][1], 0, 0, 0);
        }

        // ---- epilogue: masked-cutoff gather-weighted neighbor sum ----
        const int p = p0 + wm;
        const int bidx = p >> 8;
        const float* ybase = y + (size_t)bidx * (Adim * Fdim);
        const float fb2v0 = sFb2[fbase2 + lm];
        const float fb2v1 = sFb2[fbase2 + 32 + lm];
        float part0 = 0.0f, part1 = 0.0f;
#pragma unroll
        for (int mt = 0; mt < 2; ++mt) {
#pragma unroll
            for (int rg = 0; rg < 4; ++rg) {
                int nl0 = rbase + mt * 32 + 8 * rg + 4 * lh;
#pragma unroll
                for (int q = 0; q < 4; ++q) {
                    int nidx = nl0 + q;
                    float cm = sCm[nidx];
                    const float* yr = ybase + (size_t)sNbr[nidx] * Fdim;
                    float y0 = yr[fbase2 + lm];
                    float y1 = yr[fbase2 + 32 + lm];
                    float va = acc2[mt][0][rg * 4 + q] + fb2v0;
                    float vb = acc2[mt][1][rg * 4 + q] + fb2v1;
                    part0 += va * cm * y0;
                    part1 += vb * cm * y1;
                }
            }
        }
        part0 += __shfl_xor(part0, 32, 64);
        part1 += __shfl_xor(part1, 32, 64);
        float val = (lane < 32) ? part0 : part1;
        out[(size_t)p * Fdim + wn * 64 + lane] = val;
    }
}

// ---------------------------------------------------------------------------
extern "C" void kernel_launch(void* const* d_in, const int* in_sizes, int n_in,
                              void* d_out, int out_size, void* d_ws, size_t ws_size,
                              hipStream_t stream) {
    const float* x      = (const float*)d_in[0];
    const float* r_ij   = (const float*)d_in[1];
    const float* f_ij   = (const float*)d_in[2];
    const float* mask   = (const float*)d_in[3];
    const int*   nbr    = (const int*)d_in[4];
    const float* in2f_w = (const float*)d_in[5];
    const float* fw1    = (const float*)d_in[6];
    const float* fb1    = (const float*)d_in[7];
    const float* fw2    = (const float*)d_in[8];
    const float* fb2    = (const float*)d_in[9];
    float* out = (float*)d_out;
    float* y   = (float*)d_ws;   // (B*A, F) fp32 = 4 MB scratch

    in2f_kernel<<<(Bdim * Adim) / 16, 256, 0, stream>>>(x, in2f_w, y);
    cfconv_mfma<<<1024, 256, 0, stream>>>(r_ij, f_ij, mask, nbr,
                                          fw1, fb1, fw2, fb2, y, out);
}

// Round 3
// 261.808 us; speedup vs baseline: 3.1615x; 1.2861x over previous
//
#include <hip/hip_runtime.h>
#include <math.h>

#define Bdim 32
#define Adim 256
#define Ndim 64
#define Gdim 50
#define Fdim 128

typedef __attribute__((ext_vector_type(8)))  short short8;
typedef __attribute__((ext_vector_type(16))) float floatx16;

__device__ __forceinline__ unsigned short f2bf_u(float x) {
    unsigned u = __builtin_bit_cast(unsigned, x);
    return (unsigned short)((u + 0x7FFFu + ((u >> 16) & 1u)) >> 16);  // RNE
}
__device__ __forceinline__ unsigned pk2bf(float a, float b) {
    return (unsigned)f2bf_u(a) | ((unsigned)f2bf_u(b) << 16);
}
__device__ __forceinline__ float bf2f(unsigned short v) {
    return __builtin_bit_cast(float, ((unsigned)v) << 16);
}
// shifted softplus, numerically stable
__device__ __forceinline__ float sspf(float v) {
    float t = __expf(-fabsf(v));
    return fmaxf(v, 0.0f) + __logf(1.0f + t) - 0.69314718056f;
}
__device__ __forceinline__ short8 mk8(unsigned a, unsigned b, unsigned c, unsigned d) {
    union { unsigned u[4]; short8 s; } t;
    t.u[0] = a; t.u[1] = b; t.u[2] = c; t.u[3] = d;
    return t.s;
}

// ---------------------------------------------------------------------------
// Kernel 1: y = x @ in2f_w via bf16 MFMA, output y in bf16.
// 64 blocks x 4 waves; each wave 32 rows, all 128 f. x A-frags from global,
// wT B-frags from LDS (stride 132 shorts = 66 dw -> 2-way free b64 reads).
// ---------------------------------------------------------------------------
__global__ __launch_bounds__(256) void in2f_mfma(const float* __restrict__ x,
                                                 const float* __restrict__ w,
                                                 unsigned short* __restrict__ y) {
    __shared__ __align__(16) short sWT[128 * 132];   // 33792 B
    const int tid = threadIdx.x;
    for (int idx = tid; idx < 128 * 128; idx += 256) {
        int i = idx >> 7, f = idx & 127;
        sWT[f * 132 + i] = (short)f2bf_u(w[idx]);
    }
    __syncthreads();
    const int wv = tid >> 6, lane = tid & 63, lm = lane & 31, lh = lane >> 5;
    const int rbase = blockIdx.x * 128 + wv * 32;
    floatx16 acc[4];
#pragma unroll
    for (int jt = 0; jt < 4; ++jt)
#pragma unroll
        for (int e = 0; e < 16; ++e) acc[jt][e] = 0.0f;

    const float* xr = x + (size_t)(rbase + lm) * 128;
#pragma unroll
    for (int ks = 0; ks < 8; ++ks) {
        int g0 = ks * 16 + lh * 8;
        float4 q0 = *(const float4*)(xr + g0);
        float4 q1 = *(const float4*)(xr + g0 + 4);
        short8 a = mk8(pk2bf(q0.x, q0.y), pk2bf(q0.z, q0.w),
                       pk2bf(q1.x, q1.y), pk2bf(q1.z, q1.w));
#pragma unroll
        for (int jt = 0; jt < 4; ++jt) {
            const short* bp = &sWT[(jt * 32 + lm) * 132 + g0];
            uint2 b0 = *(const uint2*)bp;
            uint2 b1 = *(const uint2*)(bp + 4);
            acc[jt] = __builtin_amdgcn_mfma_f32_32x32x16_bf16(
                a, mk8(b0.x, b0.y, b1.x, b1.y), acc[jt], 0, 0, 0);
        }
    }
#pragma unroll
    for (int jt = 0; jt < 4; ++jt)
#pragma unroll
        for (int r = 0; r < 16; ++r) {
            int row = rbase + (r & 3) + 8 * (r >> 2) + 4 * lh;
            y[(size_t)row * 128 + jt * 32 + lm] = f2bf_u(acc[jt][r]);
        }
}

// ---------------------------------------------------------------------------
// Kernel 2: fused filter-net + cutoff + gather + neighbor reduction.
// Block = super-pair (2 sites, 128 rows); wave = 32 rows (exclusive).
// dense1: A=fw1T (LDS, stride 68), B=f_ijT (GLOBAL, converted in regs),
//         bias folded in at g=50. D (W1^T) -> dense2 A-frags via shfl_xor(32).
// dense2: A=W1 (registers!), B=fw2T (LDS, stride 132). No sW1, no sFij.
// LDS = 17408+33792+512+512+2048 = 54272 B -> 3 blocks/CU.
// ---------------------------------------------------------------------------
__global__ __launch_bounds__(256, 3) void cfconv_mfma2(
    const float* __restrict__ r_ij, const float* __restrict__ f_ij,
    const float* __restrict__ mask, const int* __restrict__ nbr,
    const float* __restrict__ fw1, const float* __restrict__ fb1,
    const float* __restrict__ fw2, const float* __restrict__ fb2,
    const unsigned short* __restrict__ ybf, float* __restrict__ out)
{
    __shared__ __align__(16) short sFw1[128 * 68];    // 17408 B (K=64 + bias@50)
    __shared__ __align__(16) short sFw2[128 * 132];   // 33792 B
    __shared__ __align__(16) float sCm[128];
    __shared__ __align__(16) int   sNbr[128];
    __shared__ __align__(16) float sRed[4 * 128];     // 2048 B

    const int tid = threadIdx.x, wv = tid >> 6, lane = tid & 63;
    const int lm = lane & 31, lh = lane >> 5;

    // ---- stage weights once per block (bf16, fragment-friendly layouts) ----
    for (int idx = tid; idx < Gdim * 128; idx += 256) {
        int g = idx >> 7, f = idx & 127;
        sFw1[f * 68 + g] = (short)f2bf_u(fw1[idx]);
    }
    for (int idx = tid; idx < 128 * 14; idx += 256) {   // g = 50..63: bias + zeros
        int f = idx / 14, g = Gdim + idx % 14;
        sFw1[f * 68 + g] = (g == Gdim) ? (short)f2bf_u(fb1[f]) : (short)0;
    }
    for (int idx = tid; idx < 128 * 128; idx += 256) {
        int h = idx >> 7, f = idx & 127;
        sFw2[f * 132 + h] = (short)f2bf_u(fw2[idx]);
    }
    float fb2v[4];
#pragma unroll
    for (int jt = 0; jt < 4; ++jt) fb2v[jt] = fb2[jt * 32 + lm];

    for (int it = 0; it < 4; ++it) {
        const int sp = blockIdx.x + 1024 * it;
        // ---- stage cutoff*mask + neighbor indices for the 2 sites ----
        if (tid < 128) {
            int site = sp * 2 + (tid >> 6), n = tid & 63;
            float r = r_ij[(size_t)site * Ndim + n];
            float c = 0.5f * (__cosf(r * 0.62831853071796f) + 1.0f);
            c = (r < 5.0f) ? c : 0.0f;
            sCm[tid]  = c * mask[(size_t)site * Ndim + n];
            sNbr[tid] = nbr[(size_t)site * Ndim + n];
        }
        // ---- dense1 B-frags from GLOBAL f_ij (issued before barrier) ----
        const int ps = sp * 2 + (wv >> 1);      // site for this wave
        const int nb = (wv & 1) * 32;           // n-range base within site
        const float* fr = f_ij + ((size_t)ps * Ndim + nb + lm) * Gdim;
        unsigned bfr[4][4];
#pragma unroll
        for (int ks = 0; ks < 3; ++ks) {
            int g0 = ks * 16 + lh * 8;
            float2 q0 = *(const float2*)(fr + g0);
            float2 q1 = *(const float2*)(fr + g0 + 2);
            float2 q2 = *(const float2*)(fr + g0 + 4);
            float2 q3 = *(const float2*)(fr + g0 + 6);
            bfr[ks][0] = pk2bf(q0.x, q0.y); bfr[ks][1] = pk2bf(q1.x, q1.y);
            bfr[ks][2] = pk2bf(q2.x, q2.y); bfr[ks][3] = pk2bf(q3.x, q3.y);
        }
        if (lh == 0) {   // g 48,49 valid; g=50 is the bias column (B=1.0)
            float2 q = *(const float2*)(fr + 48);
            bfr[3][0] = pk2bf(q.x, q.y); bfr[3][1] = 0x00003F80u;
            bfr[3][2] = 0u; bfr[3][3] = 0u;
        } else { bfr[3][0] = bfr[3][1] = bfr[3][2] = bfr[3][3] = 0u; }
        __syncthreads();   // B1

        // ---- dense1: W1^T per f-tile; ssp; convert D-frags -> A2-frags ----
        unsigned A2[8][4];
#pragma unroll
        for (int ft = 0; ft < 4; ++ft) {
            floatx16 a1;
#pragma unroll
            for (int e = 0; e < 16; ++e) a1[e] = 0.0f;
#pragma unroll
            for (int ks = 0; ks < 4; ++ks) {
                const short* ap = &sFw1[(ft * 32 + lm) * 68 + ks * 16 + lh * 8];
                uint2 a0 = *(const uint2*)ap;
                uint2 a1v = *(const uint2*)(ap + 4);
                a1 = __builtin_amdgcn_mfma_f32_32x32x16_bf16(
                    mk8(a0.x, a0.y, a1v.x, a1v.y),
                    mk8(bfr[ks][0], bfr[ks][1], bfr[ks][2], bfr[ks][3]),
                    a1, 0, 0, 0);
            }
            unsigned P[8], X[8];
#pragma unroll
            for (int q = 0; q < 8; ++q)
                P[q] = pk2bf(sspf(a1[2 * q]), sspf(a1[2 * q + 1]));
#pragma unroll
            for (int q = 0; q < 8; ++q) X[q] = (unsigned)__shfl_xor((int)P[q], 32);
            // chunk0 (h-local 0..15), chunk1 (h-local 16..31)
            A2[2*ft][0]   = lh ? X[2] : P[0];  A2[2*ft][1]   = lh ? X[3] : P[1];
            A2[2*ft][2]   = lh ? P[2] : X[0];  A2[2*ft][3]   = lh ? P[3] : X[1];
            A2[2*ft+1][0] = lh ? X[6] : P[4];  A2[2*ft+1][1] = lh ? X[7] : P[5];
            A2[2*ft+1][2] = lh ? P[6] : X[4];  A2[2*ft+1][3] = lh ? P[7] : X[5];
        }

        // ---- dense2: A = W1 (regs), B = fw2T (LDS) ----
        floatx16 acc2[4];
#pragma unroll
        for (int jt = 0; jt < 4; ++jt)
#pragma unroll
            for (int e = 0; e < 16; ++e) acc2[jt][e] = 0.0f;
#pragma unroll
        for (int ks = 0; ks < 8; ++ks) {
            short8 a = mk8(A2[ks][0], A2[ks][1], A2[ks][2], A2[ks][3]);
#pragma unroll
            for (int jt = 0; jt < 4; ++jt) {
                const short* bp = &sFw2[(jt * 32 + lm) * 132 + ks * 16 + lh * 8];
                uint2 b0 = *(const uint2*)bp;
                uint2 b1 = *(const uint2*)(bp + 4);
                acc2[jt] = __builtin_amdgcn_mfma_f32_32x32x16_bf16(
                    a, mk8(b0.x, b0.y, b1.x, b1.y), acc2[jt], 0, 0, 0);
            }
        }

        // ---- epilogue: out[f] += cm[n]*(W2[n,f]+fb2[f])*y[nbr[n],f] ----
        float cmv[16]; int nbv[16];
#pragma unroll
        for (int rq = 0; rq < 4; ++rq) {   // rloc = rq*8 + lh*4 + q  (broadcast reads)
            float4 c4 = *(const float4*)&sCm[wv * 32 + rq * 8 + lh * 4];
            int4   n4 = *(const int4*)&sNbr[wv * 32 + rq * 8 + lh * 4];
            cmv[rq*4+0] = c4.x; cmv[rq*4+1] = c4.y; cmv[rq*4+2] = c4.z; cmv[rq*4+3] = c4.w;
            nbv[rq*4+0] = n4.x; nbv[rq*4+1] = n4.y; nbv[rq*4+2] = n4.z; nbv[rq*4+3] = n4.w;
        }
        const int bofs = (ps >> 8) * Adim;
        float part[4] = {0.f, 0.f, 0.f, 0.f};
#pragma unroll
        for (int r = 0; r < 16; ++r) {
            float cm = cmv[r];
            const unsigned short* yr = ybf + (size_t)(bofs + nbv[r]) * 128;
#pragma unroll
            for (int jt = 0; jt < 4; ++jt) {
                float yv = bf2f(yr[jt * 32 + lm]);
                part[jt] += (acc2[jt][r] + fb2v[jt]) * cm * yv;
            }
        }
#pragma unroll
        for (int jt = 0; jt < 4; ++jt) {
            float s = part[jt] + __shfl_xor(part[jt], 32);
            if (lh == 0) sRed[wv * 128 + jt * 32 + lm] = s;
        }
        __syncthreads();   // B2
        {
            int s = tid >> 7, f = tid & 127;
            out[(size_t)(sp * 2 + s) * 128 + f] =
                sRed[(2 * s) * 128 + f] + sRed[(2 * s + 1) * 128 + f];
        }
    }
}

// ---------------------------------------------------------------------------
extern "C" void kernel_launch(void* const* d_in, const int* in_sizes, int n_in,
                              void* d_out, int out_size, void* d_ws, size_t ws_size,
                              hipStream_t stream) {
    const float* x      = (const float*)d_in[0];
    const float* r_ij   = (const float*)d_in[1];
    const float* f_ij   = (const float*)d_in[2];
    const float* mask   = (const float*)d_in[3];
    const int*   nbr    = (const int*)d_in[4];
    const float* in2f_w = (const float*)d_in[5];
    const float* fw1    = (const float*)d_in[6];
    const float* fb1    = (const float*)d_in[7];
    const float* fw2    = (const float*)d_in[8];
    const float* fb2    = (const float*)d_in[9];
    float* out = (float*)d_out;
    unsigned short* y = (unsigned short*)d_ws;   // (B*A, F) bf16 = 2 MB scratch

    in2f_mfma<<<64, 256, 0, stream>>>(x, in2f_w, y);
    cfconv_mfma2<<<1024, 256, 0, stream>>>(r_ij, f_ij, mask, nbr,
                                           fw1, fb1, fw2, fb2, y, out);
}

// Round 6
// 253.608 us; speedup vs baseline: 3.2638x; 1.0323x over previous
//
#include <hip/hip_runtime.h>
#include <hip/hip_bf16.h>
#include <math.h>

#define Bdim 32
#define Adim 256
#define Ndim 64
#define Gdim 50
#define Fdim 128

typedef __attribute__((ext_vector_type(8)))  short short8;
typedef __attribute__((ext_vector_type(16))) float floatx16;

__device__ __forceinline__ unsigned short f2bf_u(float x) {
    __hip_bfloat16 h = __float2bfloat16(x);
    return __builtin_bit_cast(unsigned short, h);
}
__device__ __forceinline__ unsigned pk2bf(float a, float b) {
    return (unsigned)f2bf_u(a) | ((unsigned)f2bf_u(b) << 16);
}
__device__ __forceinline__ float bf2f(unsigned short v) {
    return __builtin_bit_cast(float, ((unsigned)v) << 16);
}
// shifted softplus, numerically stable
__device__ __forceinline__ float sspf(float v) {
    float t = __expf(-fabsf(v));
    return fmaxf(v, 0.0f) + __logf(1.0f + t) - 0.69314718056f;
}
__device__ __forceinline__ short8 mk8(unsigned a, unsigned b, unsigned c, unsigned d) {
    union { unsigned u[4]; short8 s; } t;
    t.u[0] = a; t.u[1] = b; t.u[2] = c; t.u[3] = d;
    return t.s;
}

// ---------------------------------------------------------------------------
// Kernel 1: y = x @ in2f_w via bf16 MFMA, y in bf16. Fully coalesced staging:
// x tile and w^T staged to LDS via lane-linear float2 loads (512 B/inst).
// 64 blocks x 128 rows; wave = 32 rows x all 128 f.
// ---------------------------------------------------------------------------
__global__ __launch_bounds__(256) void in2f_mfma2(const float* __restrict__ x,
                                                  const float* __restrict__ w,
                                                  unsigned short* __restrict__ y) {
    __shared__ short sWT[128 * 132];   // w^T[f][i]  33792 B
    __shared__ short sX [128 * 132];   // x[row][i]  33792 B
    const int tid = threadIdx.x;

    // stage w transposed (linear coalesced read, b16 scatter write)
#pragma unroll 4
    for (int k = 0; k < 32; ++k) {
        int idx = tid + k * 256;             // float2 index, 8192 total
        float2 v = *(const float2*)(w + 2 * idx);
        int i = idx >> 6;                    // input channel (w row)
        int f = (2 * idx) & 127;
        sWT[f * 132 + i]       = (short)f2bf_u(v.x);
        sWT[(f + 1) * 132 + i] = (short)f2bf_u(v.y);
    }
    // stage x tile (linear coalesced read, packed u32 write)
    const float* xb = x + (size_t)blockIdx.x * (128 * 128);
#pragma unroll 4
    for (int k = 0; k < 32; ++k) {
        int idx = tid + k * 256;
        float2 v = *(const float2*)(xb + 2 * idx);
        int row = idx >> 6;
        int i = (2 * idx) & 127;
        *(unsigned*)&sX[row * 132 + i] = pk2bf(v.x, v.y);
    }
    __syncthreads();

    const int wv = tid >> 6, lane = tid & 63, lm = lane & 31, lh = lane >> 5;
    floatx16 acc[4];
#pragma unroll
    for (int jt = 0; jt < 4; ++jt)
#pragma unroll
        for (int e = 0; e < 16; ++e) acc[jt][e] = 0.0f;

#pragma unroll
    for (int ks = 0; ks < 8; ++ks) {
        int g0 = ks * 16 + lh * 8;
        const short* ap = &sX[(wv * 32 + lm) * 132 + g0];
        uint2 a0 = *(const uint2*)ap;
        uint2 a1 = *(const uint2*)(ap + 4);
        short8 a = mk8(a0.x, a0.y, a1.x, a1.y);
#pragma unroll
        for (int jt = 0; jt < 4; ++jt) {
            const short* bp = &sWT[(jt * 32 + lm) * 132 + g0];
            uint2 b0 = *(const uint2*)bp;
            uint2 b1 = *(const uint2*)(bp + 4);
            acc[jt] = __builtin_amdgcn_mfma_f32_32x32x16_bf16(
                a, mk8(b0.x, b0.y, b1.x, b1.y), acc[jt], 0, 0, 0);
        }
    }
    const int rbase = blockIdx.x * 128 + wv * 32;
#pragma unroll
    for (int jt = 0; jt < 4; ++jt)
#pragma unroll
        for (int r = 0; r < 16; ++r) {
            int row = rbase + (r & 3) + 8 * (r >> 2) + 4 * lh;
            y[(size_t)row * 128 + jt * 32 + lm] = f2bf_u(acc[jt][r]);
        }
}

// ---------------------------------------------------------------------------
// Kernel 2: fused filter-net + cutoff + gather + neighbor reduction.
// Block = super-pair (2 sites, 128 rows); wave = 32 rows exclusive.
// f_ij staged to LDS via coalesced linear float2 loads (tile = 2*64*50 =
// 6400 floats = 3200 float2 -> 13 guarded iters); bias column (g=50, B=1.0)
// baked into the tile once. dense1 A=fw1T(LDS), B=f_ij(LDS); W1 stays in
// registers (shfl remap); dense2 A=regs, B=fw2T(LDS).
// LDS = 17408+33792+15392+512+512+2048 = 69664 B -> 2 blocks/CU.
// ---------------------------------------------------------------------------
#define SF1 68    // sFw1 stride (shorts): 34 dw -> 2-way free b64
#define SF2 132   // sFw2 stride: 66 dw -> 2-way free b64
#define SFI 60    // sFij stride: 30 dw -> 2-way free b64

__global__ __launch_bounds__(256, 2) void cfconv_mfma3(
    const float* __restrict__ r_ij, const float* __restrict__ f_ij,
    const float* __restrict__ mask, const int* __restrict__ nbr,
    const float* __restrict__ fw1, const float* __restrict__ fb1,
    const float* __restrict__ fw2, const float* __restrict__ fb2,
    const unsigned short* __restrict__ ybf, float* __restrict__ out)
{
    __shared__ short sFw1[128 * SF1];        // fw1T[f][g], bias col at g=50
    __shared__ short sFw2[128 * SF2];        // fw2T[f][h]
    __shared__ short sFij[128 * SFI + 16];   // [(site,n)][g] bf16, +tail pad
    __shared__ float sCm[128];
    __shared__ int   sNbr[128];
    __shared__ float sRed[4 * 128];

    const int tid = threadIdx.x, wv = tid >> 6, lane = tid & 63;
    const int lm = lane & 31, lh = lane >> 5;

    // ---- stage weights once per block ----
    for (int idx = tid; idx < Gdim * 128; idx += 256) {
        int g = idx >> 7, f = idx & 127;
        sFw1[f * SF1 + g] = (short)f2bf_u(fw1[idx]);
    }
    for (int idx = tid; idx < 128 * 14; idx += 256) {   // g=50: fb1; 51..63: 0
        int f = idx / 14, g = Gdim + idx % 14;
        sFw1[f * SF1 + g] = (g == Gdim) ? (short)f2bf_u(fb1[f]) : (short)0;
    }
    for (int idx = tid; idx < 128 * 128; idx += 256) {
        int h = idx >> 7, f = idx & 127;
        sFw2[f * SF2 + h] = (short)f2bf_u(fw2[idx]);
    }
    // sFij constant columns g=50..59 (bias 1.0 at g=50, zeros after) + pad
    for (int idx = tid; idx < 128 * 5; idx += 256) {
        int row = idx / 5, k = idx - row * 5;
        *(unsigned*)&sFij[row * SFI + 50 + 2 * k] = (k == 0) ? 0x00003F80u : 0u;
    }
    if (tid < 8) *(unsigned*)&sFij[128 * SFI + 2 * tid] = 0u;

    float fb2v[4];
#pragma unroll
    for (int jt = 0; jt < 4; ++jt) fb2v[jt] = fb2[jt * 32 + lm];

    for (int it = 0; it < 4; ++it) {
        const int sp = blockIdx.x + 1024 * it;

        // ---- stage f_ij tile: linear coalesced float2 -> packed bf16 LDS ----
        // tile = 2 sites * 64 n * 50 g = 6400 floats = 3200 float2
        const float* fp = f_ij + (size_t)sp * (2 * Ndim * Gdim);
#pragma unroll
        for (int k = 0; k < 13; ++k) {
            int idx = tid + k * 256;               // float2 index
            if (idx < 3200) {
                float2 v = *(const float2*)(fp + 2 * idx);
                int row = idx / 25;                // = (2*idx)/50
                int g   = 2 * idx - row * 50;
                *(unsigned*)&sFij[row * SFI + g] = pk2bf(v.x, v.y);
            }
        }
        if (tid < 128) {
            int site = sp * 2 + (tid >> 6), n = tid & 63;
            float r = r_ij[(size_t)site * Ndim + n];
            float c = 0.5f * (__cosf(r * 0.62831853071796f) + 1.0f);
            c = (r < 5.0f) ? c : 0.0f;
            sCm[tid]  = c * mask[(size_t)site * Ndim + n];
            sNbr[tid] = nbr[(size_t)site * Ndim + n];
        }
        __syncthreads();   // B1: staging done

        // ---- dense1: A = fw1T (LDS), B = f_ij (LDS); ssp; remap to A2 ----
        const int rowb = wv * 32;   // this wave's rows in the 128-row tile
        unsigned A2[8][4];
#pragma unroll
        for (int ft = 0; ft < 4; ++ft) {
            floatx16 a1;
#pragma unroll
            for (int e = 0; e < 16; ++e) a1[e] = 0.0f;
#pragma unroll
            for (int ks = 0; ks < 4; ++ks) {
                int g0 = ks * 16 + lh * 8;
                const short* ap = &sFw1[(ft * 32 + lm) * SF1 + g0];
                uint2 a0 = *(const uint2*)ap;
                uint2 a1v = *(const uint2*)(ap + 4);
                const short* bp = &sFij[(rowb + lm) * SFI + g0];
                uint2 b0 = *(const uint2*)bp;
                uint2 b1v = *(const uint2*)(bp + 4);
                a1 = __builtin_amdgcn_mfma_f32_32x32x16_bf16(
                    mk8(a0.x, a0.y, a1v.x, a1v.y),
                    mk8(b0.x, b0.y, b1v.x, b1v.y), a1, 0, 0, 0);
            }
            unsigned P[8], X[8];
#pragma unroll
            for (int q = 0; q < 8; ++q)
                P[q] = pk2bf(sspf(a1[2 * q]), sspf(a1[2 * q + 1]));
#pragma unroll
            for (int q = 0; q < 8; ++q) X[q] = (unsigned)__shfl_xor((int)P[q], 32);
            A2[2*ft][0]   = lh ? X[2] : P[0];  A2[2*ft][1]   = lh ? X[3] : P[1];
            A2[2*ft][2]   = lh ? P[2] : X[0];  A2[2*ft][3]   = lh ? P[3] : X[1];
            A2[2*ft+1][0] = lh ? X[6] : P[4];  A2[2*ft+1][1] = lh ? X[7] : P[5];
            A2[2*ft+1][2] = lh ? P[6] : X[4];  A2[2*ft+1][3] = lh ? P[7] : X[5];
        }

        // ---- dense2: A = W1 (regs), B = fw2T (LDS) ----
        floatx16 acc2[4];
#pragma unroll
        for (int jt = 0; jt < 4; ++jt)
#pragma unroll
            for (int e = 0; e < 16; ++e) acc2[jt][e] = 0.0f;
#pragma unroll
        for (int ks = 0; ks < 8; ++ks) {
            short8 a = mk8(A2[ks][0], A2[ks][1], A2[ks][2], A2[ks][3]);
#pragma unroll
            for (int jt = 0; jt < 4; ++jt) {
                const short* bp = &sFw2[(jt * 32 + lm) * SF2 + ks * 16 + lh * 8];
                uint2 b0 = *(const uint2*)bp;
                uint2 b1 = *(const uint2*)(bp + 4);
                acc2[jt] = __builtin_amdgcn_mfma_f32_32x32x16_bf16(
                    a, mk8(b0.x, b0.y, b1.x, b1.y), acc2[jt], 0, 0, 0);
            }
        }

        // ---- epilogue: out[f] += cm[n]*(W2[n,f]+fb2[f])*y[nbr[n],f] ----
        const int ps = sp * 2 + (wv >> 1);
        float cmv[16]; int nbv[16];
#pragma unroll
        for (int rq = 0; rq < 4; ++rq) {
            float4 c4 = *(const float4*)&sCm[wv * 32 + rq * 8 + lh * 4];
            int4   n4 = *(const int4*)&sNbr[wv * 32 + rq * 8 + lh * 4];
            cmv[rq*4+0] = c4.x; cmv[rq*4+1] = c4.y; cmv[rq*4+2] = c4.z; cmv[rq*4+3] = c4.w;
            nbv[rq*4+0] = n4.x; nbv[rq*4+1] = n4.y; nbv[rq*4+2] = n4.z; nbv[rq*4+3] = n4.w;
        }
        const int bofs = (ps >> 8) * Adim;
        float part[4] = {0.f, 0.f, 0.f, 0.f};
#pragma unroll
        for (int r = 0; r < 16; ++r) {
            float cm = cmv[r];
            const unsigned short* yr = ybf + (size_t)(bofs + nbv[r]) * 128;
#pragma unroll
            for (int jt = 0; jt < 4; ++jt) {
                float yv = bf2f(yr[jt * 32 + lm]);
                part[jt] += (acc2[jt][r] + fb2v[jt]) * cm * yv;
            }
        }
#pragma unroll
        for (int jt = 0; jt < 4; ++jt) {
            float s = part[jt] + __shfl_xor(part[jt], 32);
            if (lh == 0) sRed[wv * 128 + jt * 32 + lm] = s;
        }
        __syncthreads();   // B2: sRed complete, all frag reads of this iter done
        {
            int s = tid >> 7, f = tid & 127;
            out[(size_t)(sp * 2 + s) * 128 + f] =
                sRed[(2 * s) * 128 + f] + sRed[(2 * s + 1) * 128 + f];
        }
    }
}

// ---------------------------------------------------------------------------
extern "C" void kernel_launch(void* const* d_in, const int* in_sizes, int n_in,
                              void* d_out, int out_size, void* d_ws, size_t ws_size,
                              hipStream_t stream) {
    const float* x      = (const float*)d_in[0];
    const float* r_ij   = (const float*)d_in[1];
    const float* f_ij   = (const float*)d_in[2];
    const float* mask   = (const float*)d_in[3];
    const int*   nbr    = (const int*)d_in[4];
    const float* in2f_w = (const float*)d_in[5];
    const float* fw1    = (const float*)d_in[6];
    const float* fb1    = (const float*)d_in[7];
    const float* fw2    = (const float*)d_in[8];
    const float* fb2    = (const float*)d_in[9];
    float* out = (float*)d_out;
    unsigned short* y = (unsigned short*)d_ws;   // (B*A, F) bf16 = 2 MB scratch

    in2f_mfma2<<<64, 256, 0, stream>>>(x, in2f_w, y);
    cfconv_mfma3<<<1024, 256, 0, stream>>>(r_ij, f_ij, mask, nbr,
                                           fw1, fb1, fw2, fb2, y, out);
}